// Round 8
// baseline (334.034 us; speedup 1.0000x reference)
//
#include <hip/hip_runtime.h>
#include <math.h>

typedef __attribute__((ext_vector_type(4))) float f32x4;
typedef __attribute__((ext_vector_type(4))) short s16x4;

#define LOG2E   1.4426950408889634f
#define EPSV    2.220446049250313e-16f
#define HLOG2PI 0.9189385332046727f

// Schraudolph-to-bf16: U = e128 + MAGIC (f32 add rounds to ulp=1 since
// U in [2^23,2^24)); low16(bits(U)) == bf16 bits of ~2^(e128/128).
// MAGIC = 1.5*2^23 + 127*128 + (128*sigma - 0.5), sigma = -0.0573; folded
// into 'a' at prep time.
#define MAGICC  12599160.0f

static __device__ __forceinline__ float fexp2(float x) {
  return __builtin_amdgcn_exp2f(x);
}

// [hi16(f1)]:[hi16(f0)] -> bf16 trunc pack, one v_perm_b32
static __device__ __forceinline__ unsigned pk_bf16t(float f0, float f1) {
  return __builtin_amdgcn_perm(__builtin_bit_cast(unsigned, f1),
                               __builtin_bit_cast(unsigned, f0), 0x07060302u);
}
// [lo16(u1)]:[lo16(u0)] -> Schraudolph bf16 bits, one v_perm_b32
static __device__ __forceinline__ unsigned pk_lo16_2(float u0, float u1) {
  return __builtin_amdgcn_perm(__builtin_bit_cast(unsigned, u1),
                               __builtin_bit_cast(unsigned, u0), 0x05040100u);
}

static __device__ __forceinline__ float rdlane(float v, int lane) {
  return __builtin_bit_cast(float,
      __builtin_amdgcn_readlane(__builtin_bit_cast(int, v), lane));
}

// ---------------------------------------------------------------------------
// Prep: fold log_softmax(W_logits, axis=1), softplus(pre_sigma), mu into
// per-entry quadratic coefficients scaled by 128*log2(e), Schraudolph magic
// folded into 'a':  U[m,k,j](x) = a + b*x + c*x^2 ; lo16(bits(U)) = bf16(R).
// Layout: group g = m*64 + k*4 + q  (q = j/4) -> 3 consecutive float4 {a,b,c}.
// ---------------------------------------------------------------------------
__global__ void tt_prep(const float* __restrict__ Wl,
                        const float* __restrict__ mu,
                        const float* __restrict__ ps,
                        float* __restrict__ abc, int M) {
  int g = blockIdx.x * blockDim.x + threadIdx.x;
  if (g >= M * 64) return;
  int m = g >> 6;
  int k = (g >> 2) & 15;
  int q = g & 3;
  const float SC = 128.0f * LOG2E;
  float av[4], bv[4], cv[4];
#pragma unroll
  for (int i = 0; i < 4; ++i) {
    int j = q * 4 + i;
    int base = m * 256 + j;               // stride 16 over k'
    float mx = -INFINITY;
    for (int kk = 0; kk < 16; ++kk) mx = fmaxf(mx, Wl[base + kk * 16]);
    float s = 0.f;
    for (int kk = 0; kk < 16; ++kk) s += expf(Wl[base + kk * 16] - mx);
    float lse = mx + logf(s);
    int idx = m * 256 + k * 16 + j;
    float logw = Wl[idx] - lse;
    float p  = ps[idx];
    float sg = (p > 20.f) ? p : log1pf(expf(p));   // softplus
    float inv  = 1.0f / sg;
    float inv2 = inv * inv;
    float muv  = mu[idx];
    av[i] = SC * (logw - logf(sg) - HLOG2PI - 0.5f * muv * muv * inv2) + MAGICC;
    bv[i] = SC * (muv * inv2);
    cv[i] = SC * (-0.5f * inv2);
  }
  f32x4* o = (f32x4*)abc + (long)g * 3;
  o[0] = (f32x4){av[0], av[1], av[2], av[3]};
  o[1] = (f32x4){bv[0], bv[1], bv[2], bv[3]};
  o[2] = (f32x4){cv[0], cv[1], cv[2], cv[3]};
}

// ---------------------------------------------------------------------------
// Specialized main for M == 32. One wave = 8 samples, state packed bf16.
// Allocator-friendly body: x broadcast lives in an SGPR (readlane), the 4
// quadratics are 8 scalar v_fma_f32 with the SGPR as one source (VOP3 allows
// 1 SGPR operand) — no f32x2 tuples, no {xs,xs} materialization, no
// even-align copies. __launch_bounds__(256,3) gives ~170 VGPRs so nothing
// is forced into AGPRs (no v_accvgpr churn).
// Per-iter: readlane + 8 fma + 2 perm + 2 pk_max_i16 + mfma + 2 perm.
// ---------------------------------------------------------------------------
__global__ __launch_bounds__(256, 3)
void tt_main32(const float* __restrict__ X,
               const float* __restrict__ wk0_logits,
               const float* __restrict__ abc,
               float* __restrict__ out, int N) {
  const int l = (int)(threadIdx.x & 63u);
  const int wave = __builtin_amdgcn_readfirstlane((int)(threadIdx.x >> 6));
  const int c = l & 15;   // A row / D col
  const int q = l >> 4;   // quad

  long nb = ((long)blockIdx.x * 4 + wave) * 8;
  if (nb > (long)N - 8) nb = (long)N - 8;   // tail clamp (duplicate work ok)

  // wk0 = softmax(wk0_logits); seed packed state with wk0 (B-frag layout)
  float wl = wk0_logits[c];
  float mx = wl;
#pragma unroll
  for (int d = 1; d < 16; d <<= 1) mx = fmaxf(mx, __shfl_xor(mx, d, 64));
  float ew = fexp2((wl - mx) * LOG2E);
  float sw = ew;
#pragma unroll
  for (int d = 1; d < 16; d <<= 1) sw += __shfl_xor(sw, d, 64);
  float w0 = ew / sw;

  f32x4 q0;
#pragma unroll
  for (int i = 0; i < 4; ++i) q0[i] = __shfl(w0, 4 * q + i, 64);

  unsigned Qx[8], Qy[8];
#pragma unroll
  for (int s = 0; s < 8; ++s) {
    Qx[s] = pk_bf16t(q0[0], q0[1]);
    Qy[s] = pk_bf16t(q0[2], q0[3]);
  }

  // one vector load: all 256 x values for this wave
  const float* Xn = X + nb * 32;
  float4 xq = *(const float4*)(Xn + l * 4);

  const int lofs = (c * 4 + q) * 12;        // per-lane float offset into a step
  f32x4 pa = *(const f32x4*)(abc + lofs);
  f32x4 pb = *(const f32x4*)(abc + lofs + 4);
  f32x4 pc = *(const f32x4*)(abc + lofs + 8);
  const f32x4 zero = (f32x4){0.f, 0.f, 0.f, 0.f};
  const s16x4 clmp = (s16x4){0x0080, 0x0080, 0x0080, 0x0080};

  for (int m4 = 0; m4 < 32; m4 += 4) {
    const int sb = m4 >> 2;                 // readlane base (wave-uniform)
#pragma unroll
    for (int t = 0; t < 4; ++t) {
      const int step = m4 + t;
      // clamped unconditional prefetch of next step's params
      const int ns = (step < 31) ? step + 1 : 31;
      const float* Pn = abc + (long)ns * 768 + lofs;   // uniform base + lane ofs
      f32x4 na = *(const f32x4*)(Pn);
      f32x4 nb4 = *(const f32x4*)(Pn + 4);
      f32x4 nc = *(const f32x4*)(Pn + 8);

#pragma unroll
      for (int s = 0; s < 8; ++s) {
        float xs = rdlane(((const float*)&xq)[t], sb + s * 8);  // SGPR
        float u0 = fmaf(fmaf(pc[0], xs, pb[0]), xs, pa[0]);
        float u1 = fmaf(fmaf(pc[1], xs, pb[1]), xs, pa[1]);
        float u2 = fmaf(fmaf(pc[2], xs, pb[2]), xs, pa[2]);
        float u3 = fmaf(fmaf(pc[3], xs, pb[3]), xs, pa[3]);
        uint2 at;
        at.x = pk_lo16_2(u0, u1);
        at.y = pk_lo16_2(u2, u3);
        // i16 clamp on packed patterns (2x v_pk_max_i16): wrapped/underflow
        // patterns (negative as i16) -> 0x0080 = min-normal bf16
        s16x4 af = __builtin_elementwise_max(__builtin_bit_cast(s16x4, at), clmp);
        s16x4 bf = __builtin_bit_cast(s16x4, (uint2){Qx[s], Qy[s]});
        f32x4 D = __builtin_amdgcn_mfma_f32_16x16x16bf16_1k(af, bf, zero,
                                                            0, 0, 0);
        Qx[s] = pk_bf16t(D[0], D[1]);
        Qy[s] = pk_bf16t(D[2], D[3]);
      }
      pa = na; pb = nb4; pc = nc;
    }
  }

  // y_s = sum_r v[r]: unpack bf16 state, sum 4, reduce across quads
  float res = 0.0f;
#pragma unroll
  for (int s = 0; s < 8; ++s) {
    float v0 = __builtin_bit_cast(float, Qx[s] << 16);
    float v1 = __builtin_bit_cast(float, Qx[s] & 0xFFFF0000u);
    float v2 = __builtin_bit_cast(float, Qy[s] << 16);
    float v3 = __builtin_bit_cast(float, Qy[s] & 0xFFFF0000u);
    float t = (v0 + v1) + (v2 + v3);
    t += __shfl_xor(t, 16, 64);
    t += __shfl_xor(t, 32, 64);
    if (l == s) res = t;
  }
  if (l < 8) {
    long n0 = nb + l;
    if (n0 < (long)N) out[n0] = logf(res + EPSV);
  }
}

// ---------------------------------------------------------------------------
// Generic fallback (any M) — same math, per-sample scalar x loads.
// ---------------------------------------------------------------------------
__global__ __launch_bounds__(256, 3)
void tt_main_gen(const float* __restrict__ X,
                 const float* __restrict__ wk0_logits,
                 const float* __restrict__ abc,
                 float* __restrict__ out, int N, int M) {
  const int l = (int)(threadIdx.x & 63u);
  const int wave = __builtin_amdgcn_readfirstlane((int)(threadIdx.x >> 6));
  const int c = l & 15;
  const int q = l >> 4;

  long nb = ((long)blockIdx.x * 4 + wave) * 8;
  if (nb > (long)N - 8) nb = (long)N - 8;

  float wl = wk0_logits[c];
  float mx = wl;
#pragma unroll
  for (int d = 1; d < 16; d <<= 1) mx = fmaxf(mx, __shfl_xor(mx, d, 64));
  float ew = fexp2((wl - mx) * LOG2E);
  float sw = ew;
#pragma unroll
  for (int d = 1; d < 16; d <<= 1) sw += __shfl_xor(sw, d, 64);
  float w0 = ew / sw;

  f32x4 q0;
#pragma unroll
  for (int i = 0; i < 4; ++i) q0[i] = __shfl(w0, 4 * q + i, 64);
  unsigned Qx[8], Qy[8];
#pragma unroll
  for (int s = 0; s < 8; ++s) {
    Qx[s] = pk_bf16t(q0[0], q0[1]);
    Qy[s] = pk_bf16t(q0[2], q0[3]);
  }

  const float* Xn = X + nb * (long)M;
  const f32x4* Pm = (const f32x4*)abc + (c * 4 + q) * 3;
  f32x4 pa = Pm[0], pb = Pm[1], pc = Pm[2];
  const f32x4 zero = (f32x4){0.f, 0.f, 0.f, 0.f};
  const s16x4 clmp = (s16x4){0x0080, 0x0080, 0x0080, 0x0080};

  for (int m = 0; m < M; ++m) {
    f32x4 qa, qb4, qc;
    const f32x4* Pn = Pm + 192;
    bool more = (m + 1 < M);
    if (more) { qa = Pn[0]; qb4 = Pn[1]; qc = Pn[2]; }
#pragma unroll
    for (int s = 0; s < 8; ++s) {
      float xs = Xn[(long)s * M + m];
      float u0 = fmaf(fmaf(pc[0], xs, pb[0]), xs, pa[0]);
      float u1 = fmaf(fmaf(pc[1], xs, pb[1]), xs, pa[1]);
      float u2 = fmaf(fmaf(pc[2], xs, pb[2]), xs, pa[2]);
      float u3 = fmaf(fmaf(pc[3], xs, pb[3]), xs, pa[3]);
      uint2 at;
      at.x = pk_lo16_2(u0, u1);
      at.y = pk_lo16_2(u2, u3);
      s16x4 af = __builtin_elementwise_max(__builtin_bit_cast(s16x4, at), clmp);
      s16x4 bf = __builtin_bit_cast(s16x4, (uint2){Qx[s], Qy[s]});
      f32x4 D = __builtin_amdgcn_mfma_f32_16x16x16bf16_1k(af, bf, zero,
                                                          0, 0, 0);
      Qx[s] = pk_bf16t(D[0], D[1]);
      Qy[s] = pk_bf16t(D[2], D[3]);
    }
    if (more) { pa = qa; pb = qb4; pc = qc; Pm = Pn; }
  }

  float res = 0.0f;
#pragma unroll
  for (int s = 0; s < 8; ++s) {
    float v0 = __builtin_bit_cast(float, Qx[s] << 16);
    float v1 = __builtin_bit_cast(float, Qx[s] & 0xFFFF0000u);
    float v2 = __builtin_bit_cast(float, Qy[s] << 16);
    float v3 = __builtin_bit_cast(float, Qy[s] & 0xFFFF0000u);
    float t = (v0 + v1) + (v2 + v3);
    t += __shfl_xor(t, 16, 64);
    t += __shfl_xor(t, 32, 64);
    if (l == s) res = t;
  }
  if (l < 8) {
    long n0 = nb + l;
    if (n0 < (long)N) out[n0] = logf(res + EPSV);
  }
}

extern "C" void kernel_launch(void* const* d_in, const int* in_sizes, int n_in,
                              void* d_out, int out_size, void* d_ws, size_t ws_size,
                              hipStream_t stream) {
  const float* X   = (const float*)d_in[0];
  const float* wk0 = (const float*)d_in[1];
  const float* Wl  = (const float*)d_in[2];
  const float* mu  = (const float*)d_in[3];
  const float* ps  = (const float*)d_in[4];
  int K = in_sizes[1];                 // 16
  int M = in_sizes[2] / (K * K);       // 32
  int N = in_sizes[0] / M;             // 262144
  float* abc = (float*)d_ws;           // M*64*3 float4 = 96 KB

  tt_prep<<<(M * 64 + 255) / 256, 256, 0, stream>>>(Wl, mu, ps, abc, M);
  int blocks = (int)((N + 31) / 32);
  if (M == 32) {
    tt_main32<<<blocks, 256, 0, stream>>>(X, wk0, abc, (float*)d_out, N);
  } else {
    tt_main_gen<<<blocks, 256, 0, stream>>>(X, wk0, abc, (float*)d_out, N, M);
  }
}

// Round 9
// 316.891 us; speedup vs baseline: 1.0541x; 1.0541x over previous
//
#include <hip/hip_runtime.h>
#include <math.h>

typedef __attribute__((ext_vector_type(4))) float f32x4;
typedef __attribute__((ext_vector_type(2))) float f32x2;
typedef __attribute__((ext_vector_type(4))) short s16x4;

#define LOG2E   1.4426950408889634f
#define EPSV    2.220446049250313e-16f
#define HLOG2PI 0.9189385332046727f

// Schraudolph-to-bf16: U = e128 + MAGIC (f32 add rounds to ulp=1 since
// U in [2^23,2^24)); low16(bits(U)) == bf16 bits of ~2^(e128/128).
// MAGIC = 1.5*2^23 + 127*128 + (128*sigma - 0.5), sigma = -0.0573; folded
// into 'a' at prep time.
#define MAGICC  12599160.0f

static __device__ __forceinline__ float fexp2(float x) {
  return __builtin_amdgcn_exp2f(x);
}

// [hi16(f1)]:[hi16(f0)] -> bf16 trunc pack, one v_perm_b32
static __device__ __forceinline__ unsigned pk_bf16t(float f0, float f1) {
  return __builtin_amdgcn_perm(__builtin_bit_cast(unsigned, f1),
                               __builtin_bit_cast(unsigned, f0), 0x07060302u);
}
// [lo16(u1)]:[lo16(u0)] -> Schraudolph bf16 bits, one v_perm_b32
static __device__ __forceinline__ unsigned pk_lo16(f32x2 u) {
  return __builtin_amdgcn_perm(__builtin_bit_cast(uint2, u).y,
                               __builtin_bit_cast(uint2, u).x, 0x05040100u);
}

static __device__ __forceinline__ float rdlane(float v, int lane) {
  return __builtin_bit_cast(float,
      __builtin_amdgcn_readlane(__builtin_bit_cast(int, v), lane));
}

// ---------------------------------------------------------------------------
// Prep: fold log_softmax(W_logits, axis=1), softplus(pre_sigma), mu into
// per-entry quadratic coefficients scaled by 128*log2(e), Schraudolph magic
// folded into 'a':  U[m,k,j](x) = a + b*x + c*x^2 ; lo16(bits(U)) = bf16(R).
// Layout: group g = m*64 + k*4 + q  (q = j/4) -> 3 consecutive float4 {a,b,c}.
// ---------------------------------------------------------------------------
__global__ void tt_prep(const float* __restrict__ Wl,
                        const float* __restrict__ mu,
                        const float* __restrict__ ps,
                        float* __restrict__ abc, int M) {
  int g = blockIdx.x * blockDim.x + threadIdx.x;
  if (g >= M * 64) return;
  int m = g >> 6;
  int k = (g >> 2) & 15;
  int q = g & 3;
  const float SC = 128.0f * LOG2E;
  float av[4], bv[4], cv[4];
#pragma unroll
  for (int i = 0; i < 4; ++i) {
    int j = q * 4 + i;
    int base = m * 256 + j;               // stride 16 over k'
    float mx = -INFINITY;
    for (int kk = 0; kk < 16; ++kk) mx = fmaxf(mx, Wl[base + kk * 16]);
    float s = 0.f;
    for (int kk = 0; kk < 16; ++kk) s += expf(Wl[base + kk * 16] - mx);
    float lse = mx + logf(s);
    int idx = m * 256 + k * 16 + j;
    float logw = Wl[idx] - lse;
    float p  = ps[idx];
    float sg = (p > 20.f) ? p : log1pf(expf(p));   // softplus
    float inv  = 1.0f / sg;
    float inv2 = inv * inv;
    float muv  = mu[idx];
    av[i] = SC * (logw - logf(sg) - HLOG2PI - 0.5f * muv * muv * inv2) + MAGICC;
    bv[i] = SC * (muv * inv2);
    cv[i] = SC * (-0.5f * inv2);
  }
  f32x4* o = (f32x4*)abc + (long)g * 3;
  o[0] = (f32x4){av[0], av[1], av[2], av[3]};
  o[1] = (f32x4){bv[0], bv[1], bv[2], bv[3]};
  o[2] = (f32x4){cv[0], cv[1], cv[2], cv[3]};
}

// ---------------------------------------------------------------------------
// Specialized main for M == 32. One wave = 16 samples (R5 body, 2x sample
// batch): per-t-iter fixed costs (3 param loads, addressing, rotation, loop)
// amortize over 16 sample-iterations instead of 8; wave count and
// prologue/epilogue halve. State packed bf16 (2 VGPRs/sample).
// Per-iter body: readlane + 4 pk_fma + 2 perm + 2 pk_max_i16 + mfma + 2 perm.
// ---------------------------------------------------------------------------
__global__ __launch_bounds__(256, 6)
void tt_main32(const float* __restrict__ X,
               const float* __restrict__ wk0_logits,
               const float* __restrict__ abc,
               float* __restrict__ out, int N) {
  const int l = (int)(threadIdx.x & 63u);
  const int wave = __builtin_amdgcn_readfirstlane((int)(threadIdx.x >> 6));
  const int c = l & 15;   // A row / D col
  const int q = l >> 4;   // quad

  long nb = ((long)blockIdx.x * 4 + wave) * 16;
  if (nb > (long)N - 16) nb = (long)N - 16;   // tail clamp (duplicate work ok)

  // wk0 = softmax(wk0_logits); seed packed state with wk0 (B-frag layout)
  float wl = wk0_logits[c];
  float mx = wl;
#pragma unroll
  for (int d = 1; d < 16; d <<= 1) mx = fmaxf(mx, __shfl_xor(mx, d, 64));
  float ew = fexp2((wl - mx) * LOG2E);
  float sw = ew;
#pragma unroll
  for (int d = 1; d < 16; d <<= 1) sw += __shfl_xor(sw, d, 64);
  float w0 = ew / sw;

  f32x4 q0;
#pragma unroll
  for (int i = 0; i < 4; ++i) q0[i] = __shfl(w0, 4 * q + i, 64);

  unsigned sx = pk_bf16t(q0[0], q0[1]);
  unsigned sy = pk_bf16t(q0[2], q0[3]);
  unsigned Qx[16], Qy[16];
#pragma unroll
  for (int s = 0; s < 16; ++s) { Qx[s] = sx; Qy[s] = sy; }

  // two vector loads: all 512 x values for this wave (16 samples x 32 steps)
  const float* Xn = X + nb * 32;
  float4 xq0 = *(const float4*)(Xn + l * 4);
  float4 xq1 = *(const float4*)(Xn + 256 + l * 4);

  const int lofs = (c * 4 + q) * 12;        // per-lane float offset into a step
  f32x4 pa = *(const f32x4*)(abc + lofs);
  f32x4 pb = *(const f32x4*)(abc + lofs + 4);
  f32x4 pc = *(const f32x4*)(abc + lofs + 8);
  const f32x4 zero = (f32x4){0.f, 0.f, 0.f, 0.f};
  const s16x4 clmp = (s16x4){0x0080, 0x0080, 0x0080, 0x0080};

  for (int m4 = 0; m4 < 32; m4 += 4) {
    const int sb = m4 >> 2;                 // readlane base (wave-uniform)
#pragma unroll
    for (int t = 0; t < 4; ++t) {
      const int step = m4 + t;
      // clamped unconditional prefetch of next step's params; base is
      // wave-uniform -> scalar address + lane offset
      const int ns = (step < 31) ? step + 1 : 31;
      const float* Pn = abc + (long)ns * 768 + lofs;
      f32x4 na = *(const f32x4*)(Pn);
      f32x4 nb4 = *(const f32x4*)(Pn + 4);
      f32x4 nc = *(const f32x4*)(Pn + 8);

      f32x2 c01 = {pc[0], pc[1]}, c23 = {pc[2], pc[3]};
      f32x2 b01 = {pb[0], pb[1]}, b23 = {pb[2], pb[3]};
      f32x2 a01 = {pa[0], pa[1]}, a23 = {pa[2], pa[3]};

#pragma unroll
      for (int s = 0; s < 16; ++s) {
        // sample s, step: x index s*32+step -> reg xq0/xq1, lane (s%8)*8+step/4
        float xsrc = (s < 8) ? ((const float*)&xq0)[t] : ((const float*)&xq1)[t];
        float xs = rdlane(xsrc, sb + (s & 7) * 8);
        f32x2 xx = {xs, xs};
        f32x2 u01 = __builtin_elementwise_fma(
                        __builtin_elementwise_fma(c01, xx, b01), xx, a01);
        f32x2 u23 = __builtin_elementwise_fma(
                        __builtin_elementwise_fma(c23, xx, b23), xx, a23);
        uint2 at;
        at.x = pk_lo16(u01);
        at.y = pk_lo16(u23);
        // i16 clamp on packed patterns: wrapped/underflow (negative as i16)
        // -> 0x0080 = min-normal bf16
        s16x4 af = __builtin_elementwise_max(__builtin_bit_cast(s16x4, at), clmp);
        s16x4 bf = __builtin_bit_cast(s16x4, (uint2){Qx[s], Qy[s]});
        f32x4 D = __builtin_amdgcn_mfma_f32_16x16x16bf16_1k(af, bf, zero,
                                                            0, 0, 0);
        Qx[s] = pk_bf16t(D[0], D[1]);
        Qy[s] = pk_bf16t(D[2], D[3]);
      }
      pa = na; pb = nb4; pc = nc;
    }
  }

  // y_s = sum_r v[r]: unpack bf16 state, sum 4, reduce across quads
  float res = 0.0f;
#pragma unroll
  for (int s = 0; s < 16; ++s) {
    float v0 = __builtin_bit_cast(float, Qx[s] << 16);
    float v1 = __builtin_bit_cast(float, Qx[s] & 0xFFFF0000u);
    float v2 = __builtin_bit_cast(float, Qy[s] << 16);
    float v3 = __builtin_bit_cast(float, Qy[s] & 0xFFFF0000u);
    float t = (v0 + v1) + (v2 + v3);
    t += __shfl_xor(t, 16, 64);
    t += __shfl_xor(t, 32, 64);
    if (l == s) res = t;
  }
  if (l < 16) {
    long n0 = nb + l;
    if (n0 < (long)N) out[n0] = logf(res + EPSV);
  }
}

// ---------------------------------------------------------------------------
// Generic fallback (any M) — R5 structure, 8 samples/wave.
// ---------------------------------------------------------------------------
__global__ __launch_bounds__(256, 4)
void tt_main_gen(const float* __restrict__ X,
                 const float* __restrict__ wk0_logits,
                 const float* __restrict__ abc,
                 float* __restrict__ out, int N, int M) {
  const int l = (int)(threadIdx.x & 63u);
  const int wave = __builtin_amdgcn_readfirstlane((int)(threadIdx.x >> 6));
  const int c = l & 15;
  const int q = l >> 4;

  long nb = ((long)blockIdx.x * 4 + wave) * 8;
  if (nb > (long)N - 8) nb = (long)N - 8;

  float wl = wk0_logits[c];
  float mx = wl;
#pragma unroll
  for (int d = 1; d < 16; d <<= 1) mx = fmaxf(mx, __shfl_xor(mx, d, 64));
  float ew = fexp2((wl - mx) * LOG2E);
  float sw = ew;
#pragma unroll
  for (int d = 1; d < 16; d <<= 1) sw += __shfl_xor(sw, d, 64);
  float w0 = ew / sw;

  f32x4 q0;
#pragma unroll
  for (int i = 0; i < 4; ++i) q0[i] = __shfl(w0, 4 * q + i, 64);
  unsigned Qx[8], Qy[8];
#pragma unroll
  for (int s = 0; s < 8; ++s) {
    Qx[s] = pk_bf16t(q0[0], q0[1]);
    Qy[s] = pk_bf16t(q0[2], q0[3]);
  }

  const float* Xn = X + nb * (long)M;
  const f32x4* Pm = (const f32x4*)abc + (c * 4 + q) * 3;
  f32x4 pa = Pm[0], pb = Pm[1], pc = Pm[2];
  const f32x4 zero = (f32x4){0.f, 0.f, 0.f, 0.f};
  const s16x4 clmp = (s16x4){0x0080, 0x0080, 0x0080, 0x0080};

  for (int m = 0; m < M; ++m) {
    f32x4 qa, qb4, qc;
    const f32x4* Pn = Pm + 192;
    bool more = (m + 1 < M);
    if (more) { qa = Pn[0]; qb4 = Pn[1]; qc = Pn[2]; }
#pragma unroll
    for (int s = 0; s < 8; ++s) {
      float xs = Xn[(long)s * M + m];
      f32x2 xx = {xs, xs};
      f32x2 c01 = {pc[0], pc[1]}, c23 = {pc[2], pc[3]};
      f32x2 b01 = {pb[0], pb[1]}, b23 = {pb[2], pb[3]};
      f32x2 a01 = {pa[0], pa[1]}, a23 = {pa[2], pa[3]};
      f32x2 u01 = __builtin_elementwise_fma(
                      __builtin_elementwise_fma(c01, xx, b01), xx, a01);
      f32x2 u23 = __builtin_elementwise_fma(
                      __builtin_elementwise_fma(c23, xx, b23), xx, a23);
      uint2 at;
      at.x = pk_lo16(u01);
      at.y = pk_lo16(u23);
      s16x4 af = __builtin_elementwise_max(__builtin_bit_cast(s16x4, at), clmp);
      s16x4 bf = __builtin_bit_cast(s16x4, (uint2){Qx[s], Qy[s]});
      f32x4 D = __builtin_amdgcn_mfma_f32_16x16x16bf16_1k(af, bf, zero,
                                                          0, 0, 0);
      Qx[s] = pk_bf16t(D[0], D[1]);
      Qy[s] = pk_bf16t(D[2], D[3]);
    }
    if (more) { pa = qa; pb = qb4; pc = qc; Pm = Pn; }
  }

  float res = 0.0f;
#pragma unroll
  for (int s = 0; s < 8; ++s) {
    float v0 = __builtin_bit_cast(float, Qx[s] << 16);
    float v1 = __builtin_bit_cast(float, Qx[s] & 0xFFFF0000u);
    float v2 = __builtin_bit_cast(float, Qy[s] << 16);
    float v3 = __builtin_bit_cast(float, Qy[s] & 0xFFFF0000u);
    float t = (v0 + v1) + (v2 + v3);
    t += __shfl_xor(t, 16, 64);
    t += __shfl_xor(t, 32, 64);
    if (l == s) res = t;
  }
  if (l < 8) {
    long n0 = nb + l;
    if (n0 < (long)N) out[n0] = logf(res + EPSV);
  }
}

extern "C" void kernel_launch(void* const* d_in, const int* in_sizes, int n_in,
                              void* d_out, int out_size, void* d_ws, size_t ws_size,
                              hipStream_t stream) {
  const float* X   = (const float*)d_in[0];
  const float* wk0 = (const float*)d_in[1];
  const float* Wl  = (const float*)d_in[2];
  const float* mu  = (const float*)d_in[3];
  const float* ps  = (const float*)d_in[4];
  int K = in_sizes[1];                 // 16
  int M = in_sizes[2] / (K * K);       // 32
  int N = in_sizes[0] / M;             // 262144
  float* abc = (float*)d_ws;           // M*64*3 float4 = 96 KB

  tt_prep<<<(M * 64 + 255) / 256, 256, 0, stream>>>(Wl, mu, ps, abc, M);
  if (M == 32) {
    int blocks = (int)((N + 63) / 64);
    tt_main32<<<blocks, 256, 0, stream>>>(X, wk0, abc, (float*)d_out, N);
  } else {
    int blocks = (int)((N + 31) / 32);
    tt_main_gen<<<blocks, 256, 0, stream>>>(X, wk0, abc, (float*)d_out, N, M);
  }
}

// Round 10
// 299.878 us; speedup vs baseline: 1.1139x; 1.0567x over previous
//
#include <hip/hip_runtime.h>
#include <math.h>

typedef __attribute__((ext_vector_type(4))) float f32x4;
typedef __attribute__((ext_vector_type(2))) float f32x2;
typedef __attribute__((ext_vector_type(4))) short s16x4;

#define LOG2E   1.4426950408889634f
#define EPSV    2.220446049250313e-16f
#define HLOG2PI 0.9189385332046727f

// Schraudolph-to-bf16: U = e128 + MAGIC (f32 add rounds to ulp=1 since
// U in [2^23,2^24)); low16(bits(U)) == bf16 bits of ~2^(e128/128).
// MAGIC = 1.5*2^23 + 127*128 + (128*sigma - 0.5), sigma = -0.0573; folded
// into 'a' at prep time.
#define MAGICC  12599160.0f

static __device__ __forceinline__ float fexp2(float x) {
  return __builtin_amdgcn_exp2f(x);
}

// [hi16(f1)]:[hi16(f0)] -> bf16 trunc pack, one v_perm_b32
static __device__ __forceinline__ unsigned pk_bf16t(float f0, float f1) {
  return __builtin_amdgcn_perm(__builtin_bit_cast(unsigned, f1),
                               __builtin_bit_cast(unsigned, f0), 0x07060302u);
}
// [lo16(u1)]:[lo16(u0)] -> Schraudolph bf16 bits, one v_perm_b32
static __device__ __forceinline__ unsigned pk_lo16(f32x2 u) {
  return __builtin_amdgcn_perm(__builtin_bit_cast(uint2, u).y,
                               __builtin_bit_cast(uint2, u).x, 0x05040100u);
}

static __device__ __forceinline__ float rdlane(float v, int lane) {
  return __builtin_bit_cast(float,
      __builtin_amdgcn_readlane(__builtin_bit_cast(int, v), lane));
}

// ---------------------------------------------------------------------------
// Prep: fold log_softmax(W_logits, axis=1), softplus(pre_sigma), mu into
// per-entry quadratic coefficients scaled by 128*log2(e), Schraudolph magic
// folded into 'a':  U[m,k,j](x) = a + b*x + c*x^2 ; lo16(bits(U)) = bf16(R).
// Layout: group g = m*64 + k*4 + q  (q = j/4) -> 3 consecutive float4 {a,b,c}.
// ---------------------------------------------------------------------------
__global__ void tt_prep(const float* __restrict__ Wl,
                        const float* __restrict__ mu,
                        const float* __restrict__ ps,
                        float* __restrict__ abc, int M) {
  int g = blockIdx.x * blockDim.x + threadIdx.x;
  if (g >= M * 64) return;
  int m = g >> 6;
  int k = (g >> 2) & 15;
  int q = g & 3;
  const float SC = 128.0f * LOG2E;
  float av[4], bv[4], cv[4];
#pragma unroll
  for (int i = 0; i < 4; ++i) {
    int j = q * 4 + i;
    int base = m * 256 + j;               // stride 16 over k'
    float mx = -INFINITY;
    for (int kk = 0; kk < 16; ++kk) mx = fmaxf(mx, Wl[base + kk * 16]);
    float s = 0.f;
    for (int kk = 0; kk < 16; ++kk) s += expf(Wl[base + kk * 16] - mx);
    float lse = mx + logf(s);
    int idx = m * 256 + k * 16 + j;
    float logw = Wl[idx] - lse;
    float p  = ps[idx];
    float sg = (p > 20.f) ? p : log1pf(expf(p));   // softplus
    float inv  = 1.0f / sg;
    float inv2 = inv * inv;
    float muv  = mu[idx];
    av[i] = SC * (logw - logf(sg) - HLOG2PI - 0.5f * muv * muv * inv2) + MAGICC;
    bv[i] = SC * (muv * inv2);
    cv[i] = SC * (-0.5f * inv2);
  }
  f32x4* o = (f32x4*)abc + (long)g * 3;
  o[0] = (f32x4){av[0], av[1], av[2], av[3]};
  o[1] = (f32x4){bv[0], bv[1], bv[2], bv[3]};
  o[2] = (f32x4){cv[0], cv[1], cv[2], cv[3]};
}

// ---------------------------------------------------------------------------
// Specialized main for M == 32. One wave = 16 samples, packed bf16 state
// (2 VGPRs/sample), __launch_bounds__(256,4) so ~128 VGPRs => NO spill
// (R9's launch_bounds(256,6) spilled Qx/Qy to scratch: WRITE_SIZE 22MB).
// Software-staggered pipeline inside each step: af(s+1) is computed BEFORE
// mfma(s) issues, and D(s-1) is repacked one full iteration after its mfma —
// no consumer is within ~20 cycles of its producer.
// ---------------------------------------------------------------------------
__global__ __launch_bounds__(256, 4)
void tt_main32(const float* __restrict__ X,
               const float* __restrict__ wk0_logits,
               const float* __restrict__ abc,
               float* __restrict__ out, int N) {
  const int l = (int)(threadIdx.x & 63u);
  const int wave = __builtin_amdgcn_readfirstlane((int)(threadIdx.x >> 6));
  const int c = l & 15;   // A row / D col
  const int q = l >> 4;   // quad

  long nb = ((long)blockIdx.x * 4 + wave) * 16;
  if (nb > (long)N - 16) nb = (long)N - 16;   // tail clamp (duplicate work ok)

  // wk0 = softmax(wk0_logits); seed packed state with wk0 (B-frag layout)
  float wl = wk0_logits[c];
  float mx = wl;
#pragma unroll
  for (int d = 1; d < 16; d <<= 1) mx = fmaxf(mx, __shfl_xor(mx, d, 64));
  float ew = fexp2((wl - mx) * LOG2E);
  float sw = ew;
#pragma unroll
  for (int d = 1; d < 16; d <<= 1) sw += __shfl_xor(sw, d, 64);
  float w0 = ew / sw;

  f32x4 q0;
#pragma unroll
  for (int i = 0; i < 4; ++i) q0[i] = __shfl(w0, 4 * q + i, 64);

  unsigned sx = pk_bf16t(q0[0], q0[1]);
  unsigned sy = pk_bf16t(q0[2], q0[3]);
  unsigned Qx[16], Qy[16];
#pragma unroll
  for (int s = 0; s < 16; ++s) { Qx[s] = sx; Qy[s] = sy; }

  // two vector loads: all 512 x values for this wave (16 samples x 32 steps)
  const float* Xn = X + nb * 32;
  float4 xq0 = *(const float4*)(Xn + l * 4);
  float4 xq1 = *(const float4*)(Xn + 256 + l * 4);

  const int lofs = (c * 4 + q) * 12;        // per-lane float offset into a step
  f32x4 pa = *(const f32x4*)(abc + lofs);
  f32x4 pb = *(const f32x4*)(abc + lofs + 4);
  f32x4 pc = *(const f32x4*)(abc + lofs + 8);
  const f32x4 zero = (f32x4){0.f, 0.f, 0.f, 0.f};
  const s16x4 clmp = (s16x4){0x0080, 0x0080, 0x0080, 0x0080};

  for (int m4 = 0; m4 < 32; m4 += 4) {
    const int sb = m4 >> 2;                 // readlane base (wave-uniform)
#pragma unroll
    for (int t = 0; t < 4; ++t) {
      const int step = m4 + t;
      // clamped unconditional prefetch of next step's params
      const int ns = (step < 31) ? step + 1 : 31;
      const float* Pn = abc + (long)ns * 768 + lofs;
      f32x4 na = *(const f32x4*)(Pn);
      f32x4 nb4 = *(const f32x4*)(Pn + 4);
      f32x4 nc = *(const f32x4*)(Pn + 8);

      const f32x2 c01 = {pc[0], pc[1]}, c23 = {pc[2], pc[3]};
      const f32x2 b01 = {pb[0], pb[1]}, b23 = {pb[2], pb[3]};
      const f32x2 a01 = {pa[0], pa[1]}, a23 = {pa[2], pa[3]};

      // A-frag builder for sample s at this step
      auto mk_af = [&](int s) -> s16x4 {
        float xsrc = (s < 8) ? ((const float*)&xq0)[t]
                             : ((const float*)&xq1)[t];
        float xs = rdlane(xsrc, sb + (s & 7) * 8);
        f32x2 xx = {xs, xs};
        f32x2 u01 = __builtin_elementwise_fma(
                        __builtin_elementwise_fma(c01, xx, b01), xx, a01);
        f32x2 u23 = __builtin_elementwise_fma(
                        __builtin_elementwise_fma(c23, xx, b23), xx, a23);
        uint2 at;
        at.x = pk_lo16(u01);
        at.y = pk_lo16(u23);
        return __builtin_elementwise_max(__builtin_bit_cast(s16x4, at), clmp);
      };

      // staggered pipeline: af one iter ahead; repack one iter behind
      s16x4 afc = mk_af(0);
      f32x4 Dp;
#pragma unroll
      for (int s = 0; s < 16; ++s) {
        if (s > 0) {
          Qx[s - 1] = pk_bf16t(Dp[0], Dp[1]);
          Qy[s - 1] = pk_bf16t(Dp[2], Dp[3]);
        }
        s16x4 afn = afc;
        if (s < 15) afn = mk_af(s + 1);
        s16x4 bf = __builtin_bit_cast(s16x4, (uint2){Qx[s], Qy[s]});
        Dp = __builtin_amdgcn_mfma_f32_16x16x16bf16_1k(afc, bf, zero, 0, 0, 0);
        afc = afn;
      }
      Qx[15] = pk_bf16t(Dp[0], Dp[1]);
      Qy[15] = pk_bf16t(Dp[2], Dp[3]);

      pa = na; pb = nb4; pc = nc;
    }
  }

  // y_s = sum_r v[r]: unpack bf16 state, sum 4, reduce across quads
  float res = 0.0f;
#pragma unroll
  for (int s = 0; s < 16; ++s) {
    float v0 = __builtin_bit_cast(float, Qx[s] << 16);
    float v1 = __builtin_bit_cast(float, Qx[s] & 0xFFFF0000u);
    float v2 = __builtin_bit_cast(float, Qy[s] << 16);
    float v3 = __builtin_bit_cast(float, Qy[s] & 0xFFFF0000u);
    float t = (v0 + v1) + (v2 + v3);
    t += __shfl_xor(t, 16, 64);
    t += __shfl_xor(t, 32, 64);
    if (l == s) res = t;
  }
  if (l < 16) {
    long n0 = nb + l;
    if (n0 < (long)N) out[n0] = logf(res + EPSV);
  }
}

// ---------------------------------------------------------------------------
// Generic fallback (any M) — R5 structure, 8 samples/wave.
// ---------------------------------------------------------------------------
__global__ __launch_bounds__(256, 4)
void tt_main_gen(const float* __restrict__ X,
                 const float* __restrict__ wk0_logits,
                 const float* __restrict__ abc,
                 float* __restrict__ out, int N, int M) {
  const int l = (int)(threadIdx.x & 63u);
  const int wave = __builtin_amdgcn_readfirstlane((int)(threadIdx.x >> 6));
  const int c = l & 15;
  const int q = l >> 4;

  long nb = ((long)blockIdx.x * 4 + wave) * 8;
  if (nb > (long)N - 8) nb = (long)N - 8;

  float wl = wk0_logits[c];
  float mx = wl;
#pragma unroll
  for (int d = 1; d < 16; d <<= 1) mx = fmaxf(mx, __shfl_xor(mx, d, 64));
  float ew = fexp2((wl - mx) * LOG2E);
  float sw = ew;
#pragma unroll
  for (int d = 1; d < 16; d <<= 1) sw += __shfl_xor(sw, d, 64);
  float w0 = ew / sw;

  f32x4 q0;
#pragma unroll
  for (int i = 0; i < 4; ++i) q0[i] = __shfl(w0, 4 * q + i, 64);
  unsigned Qx[8], Qy[8];
#pragma unroll
  for (int s = 0; s < 8; ++s) {
    Qx[s] = pk_bf16t(q0[0], q0[1]);
    Qy[s] = pk_bf16t(q0[2], q0[3]);
  }

  const float* Xn = X + nb * (long)M;
  const f32x4* Pm = (const f32x4*)abc + (c * 4 + q) * 3;
  f32x4 pa = Pm[0], pb = Pm[1], pc = Pm[2];
  const f32x4 zero = (f32x4){0.f, 0.f, 0.f, 0.f};
  const s16x4 clmp = (s16x4){0x0080, 0x0080, 0x0080, 0x0080};

  for (int m = 0; m < M; ++m) {
    f32x4 qa, qb4, qc;
    const f32x4* Pn = Pm + 192;
    bool more = (m + 1 < M);
    if (more) { qa = Pn[0]; qb4 = Pn[1]; qc = Pn[2]; }
#pragma unroll
    for (int s = 0; s < 8; ++s) {
      float xs = Xn[(long)s * M + m];
      f32x2 xx = {xs, xs};
      f32x2 c01 = {pc[0], pc[1]}, c23 = {pc[2], pc[3]};
      f32x2 b01 = {pb[0], pb[1]}, b23 = {pb[2], pb[3]};
      f32x2 a01 = {pa[0], pa[1]}, a23 = {pa[2], pa[3]};
      f32x2 u01 = __builtin_elementwise_fma(
                      __builtin_elementwise_fma(c01, xx, b01), xx, a01);
      f32x2 u23 = __builtin_elementwise_fma(
                      __builtin_elementwise_fma(c23, xx, b23), xx, a23);
      uint2 at;
      at.x = pk_lo16(u01);
      at.y = pk_lo16(u23);
      s16x4 af = __builtin_elementwise_max(__builtin_bit_cast(s16x4, at), clmp);
      s16x4 bf = __builtin_bit_cast(s16x4, (uint2){Qx[s], Qy[s]});
      f32x4 D = __builtin_amdgcn_mfma_f32_16x16x16bf16_1k(af, bf, zero,
                                                          0, 0, 0);
      Qx[s] = pk_bf16t(D[0], D[1]);
      Qy[s] = pk_bf16t(D[2], D[3]);
    }
    if (more) { pa = qa; pb = qb4; pc = qc; Pm = Pn; }
  }

  float res = 0.0f;
#pragma unroll
  for (int s = 0; s < 8; ++s) {
    float v0 = __builtin_bit_cast(float, Qx[s] << 16);
    float v1 = __builtin_bit_cast(float, Qx[s] & 0xFFFF0000u);
    float v2 = __builtin_bit_cast(float, Qy[s] << 16);
    float v3 = __builtin_bit_cast(float, Qy[s] & 0xFFFF0000u);
    float t = (v0 + v1) + (v2 + v3);
    t += __shfl_xor(t, 16, 64);
    t += __shfl_xor(t, 32, 64);
    if (l == s) res = t;
  }
  if (l < 8) {
    long n0 = nb + l;
    if (n0 < (long)N) out[n0] = logf(res + EPSV);
  }
}

extern "C" void kernel_launch(void* const* d_in, const int* in_sizes, int n_in,
                              void* d_out, int out_size, void* d_ws, size_t ws_size,
                              hipStream_t stream) {
  const float* X   = (const float*)d_in[0];
  const float* wk0 = (const float*)d_in[1];
  const float* Wl  = (const float*)d_in[2];
  const float* mu  = (const float*)d_in[3];
  const float* ps  = (const float*)d_in[4];
  int K = in_sizes[1];                 // 16
  int M = in_sizes[2] / (K * K);       // 32
  int N = in_sizes[0] / M;             // 262144
  float* abc = (float*)d_ws;           // M*64*3 float4 = 96 KB

  tt_prep<<<(M * 64 + 255) / 256, 256, 0, stream>>>(Wl, mu, ps, abc, M);
  if (M == 32) {
    int blocks = (int)((N + 63) / 64);
    tt_main32<<<blocks, 256, 0, stream>>>(X, wk0, abc, (float*)d_out, N);
  } else {
    int blocks = (int)((N + 31) / 32);
    tt_main_gen<<<blocks, 256, 0, stream>>>(X, wk0, abc, (float*)d_out, N, M);
  }
}